// Round 1
// baseline (3066.643 us; speedup 1.0000x reference)
//
#include <hip/hip_runtime.h>
#include <hip/hip_bf16.h>

#define GB 2  // batch elems per conv block

// ---------------- cnorm: ||cb_k||^2 per code ----------------
__global__ void cnorm_kernel(const float* __restrict__ cb, float* __restrict__ cnorm) {
    int g = blockIdx.x * blockDim.x + threadIdx.x;  // 0..8191  (q*1024+k)
    if (g >= 8 * 1024) return;
    const float* p = cb + (size_t)g * 256;
    float s = 0.f;
    for (int d = 0; d < 256; d += 4) {
        float4 v = *reinterpret_cast<const float4*>(p + d);
        s += v.x * v.x + v.y * v.y + v.z * v.z + v.w * v.w;
    }
    cnorm[g] = s;
}

// ---------------- fused conv0..conv3 + state + residual ----------------
__global__ __launch_bounds__(256)
void conv_fused_kernel(const float* __restrict__ audio,
                       const float* __restrict__ state_in,
                       const float* __restrict__ W0, const float* __restrict__ b0,
                       const float* __restrict__ W1, const float* __restrict__ b1,
                       const float* __restrict__ W2, const float* __restrict__ b2,
                       const float* __restrict__ W3, const float* __restrict__ b3,
                       float* __restrict__ out, float* __restrict__ r_ws) {
    __shared__ __align__(16) float xs[242];            // padded audio (2 left zeros)
    __shared__ __align__(16) float y0s[64 * 124];      // conv0 out, 4 left pad cols
    __shared__ __align__(16) float y1s[GB * 128 * 32]; // conv1 out, row stride 32 (30 valid)
    __shared__ __align__(16) float y2s[GB * 256 * 6];  // conv2 out

    const int tid = threadIdx.x;
    const int bbase = blockIdx.x * GB;

    if (tid < 64) {  // zero the 4 pad cols of y0 once (persist across bi)
        y0s[tid * 124 + 0] = 0.f; y0s[tid * 124 + 1] = 0.f;
        y0s[tid * 124 + 2] = 0.f; y0s[tid * 124 + 3] = 0.f;
    }

    for (int bi = 0; bi < GB; ++bi) {
        const int b = bbase + bi;
        __syncthreads();
        // ---- audio -> xs (pad 2 left) ----
        if (tid < 242) xs[tid] = (tid < 2) ? 0.f : audio[b * 240 + tid - 2];
        __syncthreads();
        // ---- conv0 (1->64, k=4, s=2) + ELU ----
        {
            const int ci = tid >> 2, tg = tid & 3;
            float4 w = *reinterpret_cast<const float4*>(W0 + ci * 4);
            float bias = b0[ci];
            for (int t = tg; t < 120; t += 4) {
                float v = bias + w.x * xs[2 * t] + w.y * xs[2 * t + 1]
                               + w.z * xs[2 * t + 2] + w.w * xs[2 * t + 3];
                y0s[ci * 124 + 4 + t] = v > 0.f ? v : expm1f(v);
            }
        }
        __syncthreads();
        // ---- conv1 (64->128, k=8, s=4) + ELU ----
        {
            const int c = tid >> 1, half = tid & 1, t0 = 15 * half;
            float acc[15];
            float bias = b1[c];
#pragma unroll
            for (int u = 0; u < 15; ++u) acc[u] = bias;
            const float* wrow = W1 + c * 512;
            for (int ci = 0; ci < 64; ++ci) {
                float4 wA = *reinterpret_cast<const float4*>(wrow + ci * 8);
                float4 wB = *reinterpret_cast<const float4*>(wrow + ci * 8 + 4);
                const float* yb = y0s + ci * 124 + 4 * t0;
#pragma unroll
                for (int u = 0; u < 15; ++u) {
                    float4 a = *reinterpret_cast<const float4*>(yb + 4 * u);
                    float4 d = *reinterpret_cast<const float4*>(yb + 4 * u + 4);
                    acc[u] += wA.x * a.x + wA.y * a.y + wA.z * a.z + wA.w * a.w
                            + wB.x * d.x + wB.y * d.y + wB.z * d.z + wB.w * d.w;
                }
            }
            float* yo = y1s + (bi * 128 + c) * 32 + t0;
#pragma unroll
            for (int u = 0; u < 15; ++u) {
                float v = acc[u];
                yo[u] = v > 0.f ? v : expm1f(v);
            }
        }
    }
    __syncthreads();
    // ---- conv2 (128->256, k=10, s=5) + ELU, all GB batch elems ----
    {
        const int c = tid;
        float acc[GB][6];
        float bias = b2[c];
#pragma unroll
        for (int bi = 0; bi < GB; ++bi)
#pragma unroll
            for (int t = 0; t < 6; ++t) acc[bi][t] = bias;
        const float* wrow = W2 + c * 1280;
        for (int ci = 0; ci < 128; ++ci) {
            float w[10];
#pragma unroll
            for (int jj = 0; jj < 5; ++jj) {
                float2 wv = *reinterpret_cast<const float2*>(wrow + ci * 10 + jj * 2);
                w[jj * 2] = wv.x; w[jj * 2 + 1] = wv.y;
            }
#pragma unroll
            for (int bi = 0; bi < GB; ++bi) {
                const float* yr = y1s + (bi * 128 + ci) * 32;
                float row[32];
#pragma unroll
                for (int k4 = 0; k4 < 8; ++k4) {
                    float4 v = *reinterpret_cast<const float4*>(yr + k4 * 4);
                    row[k4 * 4] = v.x; row[k4 * 4 + 1] = v.y;
                    row[k4 * 4 + 2] = v.z; row[k4 * 4 + 3] = v.w;
                }
                // t=0: padded window, only j>=5 valid (q = j-5)
                acc[bi][0] += w[5] * row[0] + w[6] * row[1] + w[7] * row[2]
                            + w[8] * row[3] + w[9] * row[4];
#pragma unroll
                for (int t = 1; t < 6; ++t) {
                    const int q0 = 5 * t - 5;
                    float s = 0.f;
#pragma unroll
                    for (int j = 0; j < 10; ++j) s += w[j] * row[q0 + j];
                    acc[bi][t] += s;
                }
            }
        }
#pragma unroll
        for (int bi = 0; bi < GB; ++bi)
#pragma unroll
            for (int t = 0; t < 6; ++t) {
                float v = acc[bi][t];
                y2s[(bi * 256 + c) * 6 + t] = v > 0.f ? v : expm1f(v);
            }
    }
    __syncthreads();
    // ---- conv3 (256->256, k=12, s=6): only taps j=6..11 see real data; no ELU ----
    {
        const int c = tid;
        float acc[GB];
        float bias = b3[c];
#pragma unroll
        for (int bi = 0; bi < GB; ++bi) acc[bi] = bias;
        const float* wrow = W3 + c * 3072;
        for (int ci = 0; ci < 256; ++ci) {
            float2 w01 = *reinterpret_cast<const float2*>(wrow + ci * 12 + 6);
            float2 w23 = *reinterpret_cast<const float2*>(wrow + ci * 12 + 8);
            float2 w45 = *reinterpret_cast<const float2*>(wrow + ci * 12 + 10);
#pragma unroll
            for (int bi = 0; bi < GB; ++bi) {
                const float* yr = y2s + (bi * 256 + ci) * 6;
                float2 a = *reinterpret_cast<const float2*>(yr);
                float2 d = *reinterpret_cast<const float2*>(yr + 2);
                float2 e = *reinterpret_cast<const float2*>(yr + 4);
                acc[bi] += w01.x * a.x + w01.y * a.y + w23.x * d.x + w23.y * d.y
                         + w45.x * e.x + w45.y * e.y;
            }
        }
#pragma unroll
        for (int bi = 0; bi < GB; ++bi) {
            const int b = bbase + bi;
            float y3 = acc[bi];
            r_ws[b * 256 + c] = y3;
            float4 si = *reinterpret_cast<const float4*>(state_in + b * 1024 + c * 4);
            float4 o; o.x = si.y; o.y = si.z; o.z = si.w; o.w = y3;
            *reinterpret_cast<float4*>(out + 65536 + b * 1024 + c * 4) = o;
        }
    }
}

// ---------------- RVQ: 8 levels of argmin + residual update ----------------
__device__ __forceinline__ unsigned long long distkey(float d, int k) {
    unsigned u = __float_as_uint(d);
    u = (u & 0x80000000u) ? ~u : (u | 0x80000000u);  // monotonic float->uint
    return ((unsigned long long)u << 32) | (unsigned)k;  // low idx wins ties (np argmin)
}

__global__ __launch_bounds__(512)
void rvq_kernel(const float* __restrict__ cb, const float* __restrict__ cnorm,
                const float* __restrict__ r_ws, float* __restrict__ out) {
    __shared__ __align__(16) float rs[32 * 256];   // residuals, 32 b
    __shared__ __align__(16) float cbs[64 * 130];  // [d-local 64][k-local 128], pad 130
    __shared__ int idx_sh[32];

    const int tid = threadIdx.x;
    const int b0 = blockIdx.x * 32;
    for (int it = 0; it < 4; ++it) {
        int o = (it * 512 + tid) * 4;
        *reinterpret_cast<float4*>(rs + o) =
            *reinterpret_cast<const float4*>(r_ws + b0 * 256 + o);
    }
    const int kk = tid & 63;   // k-lane
    const int bg = tid >> 6;   // wave id -> b group (4 b's)
    const int dq = tid & 15;   // tile-load dim quad
    const int Kb = tid >> 4;   // tile-load k base (0..31)

    for (int q = 0; q < 8; ++q) {
        unsigned long long keys[4];
#pragma unroll
        for (int i = 0; i < 4; ++i) keys[i] = 0xFFFFFFFFFFFFFFFFull;
        for (int kt = 0; kt < 8; ++kt) {
            const int k0 = kt * 128;
            float acc[2][4];
#pragma unroll
            for (int ci = 0; ci < 2; ++ci)
#pragma unroll
                for (int i = 0; i < 4; ++i) acc[ci][i] = 0.f;
            for (int dt = 0; dt < 4; ++dt) {
                __syncthreads();  // protect cbs overwrite
#pragma unroll
                for (int p = 0; p < 4; ++p) {
                    int K = Kb + 32 * p;
                    float4 v = *reinterpret_cast<const float4*>(
                        cb + ((size_t)(q * 1024 + k0 + K)) * 256 + dt * 64 + 4 * dq);
                    cbs[(4 * dq + 0) * 130 + K] = v.x;
                    cbs[(4 * dq + 1) * 130 + K] = v.y;
                    cbs[(4 * dq + 2) * 130 + K] = v.z;
                    cbs[(4 * dq + 3) * 130 + K] = v.w;
                }
                __syncthreads();
                const int dbase = dt * 64;
#pragma unroll 4
                for (int d4 = 0; d4 < 16; ++d4) {
                    float rr[4][4];
#pragma unroll
                    for (int i = 0; i < 4; ++i) {
                        float4 rv = *reinterpret_cast<const float4*>(
                            rs + (bg * 4 + i) * 256 + dbase + d4 * 4);
                        rr[i][0] = rv.x; rr[i][1] = rv.y; rr[i][2] = rv.z; rr[i][3] = rv.w;
                    }
#pragma unroll
                    for (int e = 0; e < 4; ++e) {
                        float2 cv = *reinterpret_cast<const float2*>(
                            cbs + (d4 * 4 + e) * 130 + 2 * kk);
#pragma unroll
                        for (int i = 0; i < 4; ++i) {
                            acc[0][i] += cv.x * rr[i][e];
                            acc[1][i] += cv.y * rr[i][e];
                        }
                    }
                }
            }
            float2 cn = *reinterpret_cast<const float2*>(cnorm + q * 1024 + k0 + 2 * kk);
#pragma unroll
            for (int i = 0; i < 4; ++i) {
                float d0 = cn.x - 2.f * acc[0][i];
                float d1 = cn.y - 2.f * acc[1][i];
                unsigned long long ka = distkey(d0, k0 + 2 * kk);
                unsigned long long kb2 = distkey(d1, k0 + 2 * kk + 1);
                if (ka < keys[i]) keys[i] = ka;
                if (kb2 < keys[i]) keys[i] = kb2;
            }
        }
        // wave-wide min-reduce (64 lanes)
#pragma unroll
        for (int i = 0; i < 4; ++i) {
            unsigned long long k = keys[i];
            for (int off = 32; off >= 1; off >>= 1) {
                unsigned long long o = __shfl_xor(k, off, 64);
                if (o < k) k = o;
            }
            if (kk == 0) idx_sh[bg * 4 + i] = (int)(k & 0xFFFFFFFFu);
        }
        __syncthreads();
        // residual update + token write
        for (int it = 0; it < 16; ++it) {
            int flat = it * 512 + tid;        // 0..8191
            int bL = flat >> 8, d = flat & 255;
            rs[bL * 256 + d] -= cb[((size_t)(q * 1024 + idx_sh[bL])) * 256 + d];
        }
        if (tid < 32) out[(b0 + tid) * 8 + q] = (float)idx_sh[tid];
        __syncthreads();
    }
}

extern "C" void kernel_launch(void* const* d_in, const int* in_sizes, int n_in,
                              void* d_out, int out_size, void* d_ws, size_t ws_size,
                              hipStream_t stream) {
    const float* audio = (const float*)d_in[0];
    const float* state = (const float*)d_in[1];
    const float* W0 = (const float*)d_in[2];
    const float* b0 = (const float*)d_in[3];
    const float* W1 = (const float*)d_in[4];
    const float* b1 = (const float*)d_in[5];
    const float* W2 = (const float*)d_in[6];
    const float* b2 = (const float*)d_in[7];
    const float* W3 = (const float*)d_in[8];
    const float* b3 = (const float*)d_in[9];
    const float* cbk = (const float*)d_in[10];
    float* out = (float*)d_out;

    float* cnorm_ws = (float*)d_ws;            // 8192 floats
    float* r_ws = cnorm_ws + 8192;             // 8192*256 floats

    cnorm_kernel<<<32, 256, 0, stream>>>(cbk, cnorm_ws);
    conv_fused_kernel<<<8192 / GB, 256, 0, stream>>>(audio, state, W0, b0, W1, b1,
                                                     W2, b2, W3, b3, out, r_ws);
    rvq_kernel<<<256, 512, 0, stream>>>(cbk, cnorm_ws, r_ws, out);
}

// Round 2
// 2438.283 us; speedup vs baseline: 1.2577x; 1.2577x over previous
//
#include <hip/hip_runtime.h>
#include <hip/hip_bf16.h>

#define GB 2  // batch elems per conv block

// ---------------- cnorm: ||cb_k||^2 per code ----------------
__global__ void cnorm_kernel(const float* __restrict__ cb, float* __restrict__ cnorm) {
    int g = blockIdx.x * blockDim.x + threadIdx.x;  // 0..8191  (q*1024+k)
    if (g >= 8 * 1024) return;
    const float* p = cb + (size_t)g * 256;
    float s = 0.f;
    for (int d = 0; d < 256; d += 4) {
        float4 v = *reinterpret_cast<const float4*>(p + d);
        s += v.x * v.x + v.y * v.y + v.z * v.z + v.w * v.w;
    }
    cnorm[g] = s;
}

// ---------------- weight transpose to lane-major layouts ----------------
// W1T[(ci*128 + c)*8 + k]   = W1[c*512  + ci*8  + k]   (ci<64,  c<128, k<8)
// W2T[(ci*256 + c)*10 + j]  = W2[c*1280 + ci*10 + j]   (ci<128, c<256, j<10)
// W3T[(ci*256 + c)*6 + jj]  = W3[c*3072 + ci*12 + 6+jj](ci<256, c<256, jj<6)
__global__ void wtrans_kernel(const float* __restrict__ W1, const float* __restrict__ W2,
                              const float* __restrict__ W3, float* __restrict__ W1T,
                              float* __restrict__ W2T, float* __restrict__ W3T) {
    int g = blockIdx.x * blockDim.x + threadIdx.x;
    if (g < 8192) {  // W1
        int ci = g >> 7, c = g & 127;
        const float* src = W1 + c * 512 + ci * 8;
        float4 a = *reinterpret_cast<const float4*>(src);
        float4 b = *reinterpret_cast<const float4*>(src + 4);
        *reinterpret_cast<float4*>(W1T + g * 8) = a;
        *reinterpret_cast<float4*>(W1T + g * 8 + 4) = b;
    }
    int g2 = g - 8192;
    if (g2 >= 0 && g2 < 32768) {  // W2
        int ci = g2 >> 8, c = g2 & 255;
        const float* src = W2 + c * 1280 + ci * 10;
        float* dst = W2T + g2 * 10;
#pragma unroll
        for (int j = 0; j < 5; ++j)
            *reinterpret_cast<float2*>(dst + 2 * j) =
                *reinterpret_cast<const float2*>(src + 2 * j);
    }
    int g3 = g - 40960;
    if (g3 >= 0 && g3 < 65536) {  // W3 (only taps 6..11 are ever used)
        int ci = g3 >> 8, c = g3 & 255;
        const float* src = W3 + c * 3072 + ci * 12 + 6;
        float* dst = W3T + g3 * 6;
#pragma unroll
        for (int j = 0; j < 3; ++j)
            *reinterpret_cast<float2*>(dst + 2 * j) =
                *reinterpret_cast<const float2*>(src + 2 * j);
    }
}

// ---------------- fused conv0..conv3 + state + residual ----------------
#define Y1S 36  // y1 row stride (padded from 30; 16B-aligned, bank-conflict-light)

__global__ __launch_bounds__(256, 2)
void conv_fused_kernel(const float* __restrict__ audio,
                       const float* __restrict__ state_in,
                       const float* __restrict__ W0, const float* __restrict__ b0,
                       const float* __restrict__ b1, const float* __restrict__ b2,
                       const float* __restrict__ b3,
                       const float* __restrict__ W1T, const float* __restrict__ W2T,
                       const float* __restrict__ W3T,
                       float* __restrict__ out, float* __restrict__ r_ws) {
    __shared__ __align__(16) float xs[244];              // padded audio (2 left zeros)
    __shared__ __align__(16) float y0s[64 * 124];        // conv0 out, 4 left pad cols
    __shared__ __align__(16) float y1s[GB * 128 * Y1S];  // conv1 out
    __shared__ __align__(16) float y2s[GB * 256 * 6];    // conv2 out

    const int tid = threadIdx.x;
    const int bbase = blockIdx.x * GB;

    if (tid < 64) {  // zero the 4 pad cols of y0 once (persist across bi)
        y0s[tid * 124 + 0] = 0.f; y0s[tid * 124 + 1] = 0.f;
        y0s[tid * 124 + 2] = 0.f; y0s[tid * 124 + 3] = 0.f;
    }

    for (int bi = 0; bi < GB; ++bi) {
        const int b = bbase + bi;
        __syncthreads();
        // ---- audio -> xs (pad 2 left) ----
        if (tid < 242) xs[tid] = (tid < 2) ? 0.f : audio[b * 240 + tid - 2];
        __syncthreads();
        // ---- conv0 (1->64, k=4, s=2) + ELU ----
        {
            const int ci = tid >> 2, tg = tid & 3;
            float4 w = *reinterpret_cast<const float4*>(W0 + ci * 4);
            float bias = b0[ci];
            for (int t = tg; t < 120; t += 4) {
                float v = bias + w.x * xs[2 * t] + w.y * xs[2 * t + 1]
                               + w.z * xs[2 * t + 2] + w.w * xs[2 * t + 3];
                y0s[ci * 124 + 4 + t] = v > 0.f ? v : expm1f(v);
            }
        }
        __syncthreads();
        // ---- conv1 (64->128, k=8, s=4) + ELU  [coalesced W1T loads] ----
        {
            const int c = tid >> 1, half = tid & 1, t0 = 15 * half;
            float acc[15];
            float bias = b1[c];
#pragma unroll
            for (int u = 0; u < 15; ++u) acc[u] = bias;
            const float* wbase = W1T + c * 8;  // + ci*1024
            for (int ci = 0; ci < 64; ++ci) {
                float4 wA = *reinterpret_cast<const float4*>(wbase + ci * 1024);
                float4 wB = *reinterpret_cast<const float4*>(wbase + ci * 1024 + 4);
                const float* yb = y0s + ci * 124 + 4 * t0;
#pragma unroll
                for (int u = 0; u < 15; ++u) {
                    float4 a = *reinterpret_cast<const float4*>(yb + 4 * u);
                    float4 d = *reinterpret_cast<const float4*>(yb + 4 * u + 4);
                    acc[u] += wA.x * a.x + wA.y * a.y + wA.z * a.z + wA.w * a.w
                            + wB.x * d.x + wB.y * d.y + wB.z * d.z + wB.w * d.w;
                }
            }
            float* yo = y1s + (bi * 128 + c) * Y1S + t0;
#pragma unroll
            for (int u = 0; u < 15; ++u) {
                float v = acc[u];
                yo[u] = v > 0.f ? v : expm1f(v);
            }
        }
    }
    __syncthreads();
    // ---- conv2 (128->256, k=10, s=5) + ELU  [coalesced W2T loads] ----
    {
        const int c = tid;
        float acc[GB][6];
        float bias = b2[c];
#pragma unroll
        for (int bi = 0; bi < GB; ++bi)
#pragma unroll
            for (int t = 0; t < 6; ++t) acc[bi][t] = bias;
        const float* wbase = W2T + c * 10;  // + ci*2560
        for (int ci = 0; ci < 128; ++ci) {
            float w[10];
#pragma unroll
            for (int jj = 0; jj < 5; ++jj) {
                float2 wv = *reinterpret_cast<const float2*>(wbase + ci * 2560 + jj * 2);
                w[jj * 2] = wv.x; w[jj * 2 + 1] = wv.y;
            }
#pragma unroll
            for (int bi = 0; bi < GB; ++bi) {
                const float* yr = y1s + (bi * 128 + ci) * Y1S;
                float row[32];
#pragma unroll
                for (int k4 = 0; k4 < 8; ++k4) {
                    float4 v = *reinterpret_cast<const float4*>(yr + k4 * 4);
                    row[k4 * 4] = v.x; row[k4 * 4 + 1] = v.y;
                    row[k4 * 4 + 2] = v.z; row[k4 * 4 + 3] = v.w;
                }
                // t=0: padded window, only j>=5 valid (q = j-5)
                acc[bi][0] += w[5] * row[0] + w[6] * row[1] + w[7] * row[2]
                            + w[8] * row[3] + w[9] * row[4];
#pragma unroll
                for (int t = 1; t < 6; ++t) {
                    const int q0 = 5 * t - 5;
                    float s = 0.f;
#pragma unroll
                    for (int j = 0; j < 10; ++j) s += w[j] * row[q0 + j];
                    acc[bi][t] += s;
                }
            }
        }
#pragma unroll
        for (int bi = 0; bi < GB; ++bi)
#pragma unroll
            for (int t = 0; t < 6; ++t) {
                float v = acc[bi][t];
                y2s[(bi * 256 + c) * 6 + t] = v > 0.f ? v : expm1f(v);
            }
    }
    __syncthreads();
    // ---- conv3 (256->256, k=12, s=6): only taps 6..11 see real data; no ELU ----
    {
        const int c = tid;
        float acc[GB];
        float bias = b3[c];
#pragma unroll
        for (int bi = 0; bi < GB; ++bi) acc[bi] = bias;
        const float* wbase = W3T + c * 6;  // + ci*1536
        for (int ci = 0; ci < 256; ++ci) {
            float2 w01 = *reinterpret_cast<const float2*>(wbase + ci * 1536);
            float2 w23 = *reinterpret_cast<const float2*>(wbase + ci * 1536 + 2);
            float2 w45 = *reinterpret_cast<const float2*>(wbase + ci * 1536 + 4);
#pragma unroll
            for (int bi = 0; bi < GB; ++bi) {
                const float* yr = y2s + (bi * 256 + ci) * 6;
                float2 a = *reinterpret_cast<const float2*>(yr);
                float2 d = *reinterpret_cast<const float2*>(yr + 2);
                float2 e = *reinterpret_cast<const float2*>(yr + 4);
                acc[bi] += w01.x * a.x + w01.y * a.y + w23.x * d.x + w23.y * d.y
                         + w45.x * e.x + w45.y * e.y;
            }
        }
#pragma unroll
        for (int bi = 0; bi < GB; ++bi) {
            const int b = bbase + bi;
            float y3 = acc[bi];
            r_ws[b * 256 + c] = y3;
            float4 si = *reinterpret_cast<const float4*>(state_in + b * 1024 + c * 4);
            float4 o; o.x = si.y; o.y = si.z; o.z = si.w; o.w = y3;
            *reinterpret_cast<float4*>(out + 65536 + b * 1024 + c * 4) = o;
        }
    }
}

// ---------------- RVQ: 8 levels of argmin + residual update ----------------
__device__ __forceinline__ unsigned long long distkey(float d, int k) {
    unsigned u = __float_as_uint(d);
    u = (u & 0x80000000u) ? ~u : (u | 0x80000000u);  // monotonic float->uint
    return ((unsigned long long)u << 32) | (unsigned)k;  // low idx wins ties (np argmin)
}

__global__ __launch_bounds__(512)
void rvq_kernel(const float* __restrict__ cb, const float* __restrict__ cnorm,
                const float* __restrict__ r_ws, float* __restrict__ out) {
    __shared__ __align__(16) float rs[32 * 256];   // residuals, 32 b
    __shared__ __align__(16) float cbs[64 * 130];  // [d-local 64][k-local 128], pad 130
    __shared__ int idx_sh[32];

    const int tid = threadIdx.x;
    const int b0 = blockIdx.x * 32;
    for (int it = 0; it < 4; ++it) {
        int o = (it * 512 + tid) * 4;
        *reinterpret_cast<float4*>(rs + o) =
            *reinterpret_cast<const float4*>(r_ws + b0 * 256 + o);
    }
    const int kk = tid & 63;   // k-lane
    const int bg = tid >> 6;   // wave id -> b group (4 b's)
    const int dq = tid & 15;   // tile-load dim quad
    const int Kb = tid >> 4;   // tile-load k base (0..31)

    for (int q = 0; q < 8; ++q) {
        unsigned long long keys[4];
#pragma unroll
        for (int i = 0; i < 4; ++i) keys[i] = 0xFFFFFFFFFFFFFFFFull;
        for (int kt = 0; kt < 8; ++kt) {
            const int k0 = kt * 128;
            float acc[2][4];
#pragma unroll
            for (int ci = 0; ci < 2; ++ci)
#pragma unroll
                for (int i = 0; i < 4; ++i) acc[ci][i] = 0.f;
            for (int dt = 0; dt < 4; ++dt) {
                __syncthreads();  // protect cbs overwrite
#pragma unroll
                for (int p = 0; p < 4; ++p) {
                    int K = Kb + 32 * p;
                    float4 v = *reinterpret_cast<const float4*>(
                        cb + ((size_t)(q * 1024 + k0 + K)) * 256 + dt * 64 + 4 * dq);
                    cbs[(4 * dq + 0) * 130 + K] = v.x;
                    cbs[(4 * dq + 1) * 130 + K] = v.y;
                    cbs[(4 * dq + 2) * 130 + K] = v.z;
                    cbs[(4 * dq + 3) * 130 + K] = v.w;
                }
                __syncthreads();
                const int dbase = dt * 64;
#pragma unroll 4
                for (int d4 = 0; d4 < 16; ++d4) {
                    float rr[4][4];
#pragma unroll
                    for (int i = 0; i < 4; ++i) {
                        float4 rv = *reinterpret_cast<const float4*>(
                            rs + (bg * 4 + i) * 256 + dbase + d4 * 4);
                        rr[i][0] = rv.x; rr[i][1] = rv.y; rr[i][2] = rv.z; rr[i][3] = rv.w;
                    }
#pragma unroll
                    for (int e = 0; e < 4; ++e) {
                        float2 cv = *reinterpret_cast<const float2*>(
                            cbs + (d4 * 4 + e) * 130 + 2 * kk);
#pragma unroll
                        for (int i = 0; i < 4; ++i) {
                            acc[0][i] += cv.x * rr[i][e];
                            acc[1][i] += cv.y * rr[i][e];
                        }
                    }
                }
            }
            float2 cn = *reinterpret_cast<const float2*>(cnorm + q * 1024 + k0 + 2 * kk);
#pragma unroll
            for (int i = 0; i < 4; ++i) {
                float d0 = cn.x - 2.f * acc[0][i];
                float d1 = cn.y - 2.f * acc[1][i];
                unsigned long long ka = distkey(d0, k0 + 2 * kk);
                unsigned long long kb2 = distkey(d1, k0 + 2 * kk + 1);
                if (ka < keys[i]) keys[i] = ka;
                if (kb2 < keys[i]) keys[i] = kb2;
            }
        }
        // wave-wide min-reduce (64 lanes)
#pragma unroll
        for (int i = 0; i < 4; ++i) {
            unsigned long long k = keys[i];
            for (int off = 32; off >= 1; off >>= 1) {
                unsigned long long o = __shfl_xor(k, off, 64);
                if (o < k) k = o;
            }
            if (kk == 0) idx_sh[bg * 4 + i] = (int)(k & 0xFFFFFFFFu);
        }
        __syncthreads();
        // residual update + token write
        for (int it = 0; it < 16; ++it) {
            int flat = it * 512 + tid;        // 0..8191
            int bL = flat >> 8, d = flat & 255;
            rs[bL * 256 + d] -= cb[((size_t)(q * 1024 + idx_sh[bL])) * 256 + d];
        }
        if (tid < 32) out[(b0 + tid) * 8 + q] = (float)idx_sh[tid];
        __syncthreads();
    }
}

extern "C" void kernel_launch(void* const* d_in, const int* in_sizes, int n_in,
                              void* d_out, int out_size, void* d_ws, size_t ws_size,
                              hipStream_t stream) {
    const float* audio = (const float*)d_in[0];
    const float* state = (const float*)d_in[1];
    const float* W0 = (const float*)d_in[2];
    const float* b0 = (const float*)d_in[3];
    const float* W1 = (const float*)d_in[4];
    const float* b1 = (const float*)d_in[5];
    const float* W2 = (const float*)d_in[6];
    const float* b2 = (const float*)d_in[7];
    const float* W3 = (const float*)d_in[8];
    const float* b3 = (const float*)d_in[9];
    const float* cbk = (const float*)d_in[10];
    float* out = (float*)d_out;

    float* cnorm_ws = (float*)d_ws;            // 8192
    float* r_ws = cnorm_ws + 8192;             // 8192*256 = 2097152
    float* W1T = r_ws + 2097152;               // 65536
    float* W2T = W1T + 65536;                  // 327680
    float* W3T = W2T + 327680;                 // 393216   (total ~11.6 MB)

    cnorm_kernel<<<32, 256, 0, stream>>>(cbk, cnorm_ws);
    wtrans_kernel<<<416, 256, 0, stream>>>(W1, W2, W3, W1T, W2T, W3T);
    conv_fused_kernel<<<8192 / GB, 256, 0, stream>>>(audio, state, W0, b0, b1, b2, b3,
                                                     W1T, W2T, W3T, out, r_ws);
    rvq_kernel<<<256, 512, 0, stream>>>(cbk, cnorm_ws, r_ws, out);
}